// Round 10
// baseline (345.104 us; speedup 1.0000x reference)
//
#include <hip/hip_runtime.h>
#include <stdint.h>

typedef __bf16 bf16;
typedef __bf16 bf16x8 __attribute__((ext_vector_type(8)));
typedef float  f32x4  __attribute__((ext_vector_type(4)));

#define NROWS 32768
#define HID   512
#define PADM  17408   // 136*128 rows per mlp (cnt = 16384 +/- 90; +11 sigma safe)

__device__ __forceinline__ void gload_lds16(const void* g, void* l) {
  __builtin_amdgcn_global_load_lds(
      (const __attribute__((address_space(1))) void*)g,
      (__attribute__((address_space(3))) void*)l, 16, 0, 0);
}

// ---------- prep: W [K][N] fp32 -> WT [N][K] bf16, chunk-of-8 XOR-preswizzled ----------
__global__ void prep_transpose(const float* __restrict__ W, bf16* __restrict__ WT,
                               int K, int N) {
  __shared__ float t[32][33];
  int k0 = blockIdx.x * 32, n0 = blockIdx.y * 32;
  int tx = threadIdx.x, ty = threadIdx.y;
#pragma unroll
  for (int p = 0; p < 4; ++p)
    t[ty + p * 8][tx] = W[(size_t)(k0 + ty + p * 8) * N + n0 + tx];
  __syncthreads();
#pragma unroll
  for (int p = 0; p < 4; ++p) {
    int n = n0 + ty + p * 8;
    int k = k0 + tx;
    int ks = (k & ~63) | (((((k >> 3) & 7) ^ (n & 7))) << 3) | (k & 7);
    WT[(size_t)n * K + ks] = (bf16)t[tx][ty + p * 8];
  }
}

// ---------- sorted stable compaction: count -> scan -> ordered write ----------
__global__ void count_rows(const int* __restrict__ masks, int* __restrict__ bcnt) {
  int i = blockIdx.x * 256 + threadIdx.x;
  int lane = threadIdx.x & 63, wv = threadIdx.x >> 6;
  unsigned long long vA = __ballot(masks[i * 3] == 0);
  __shared__ int c[4];
  if (lane == 0) c[wv] = __popcll(vA);
  __syncthreads();
  if (threadIdx.x == 0) bcnt[blockIdx.x] = c[0] + c[1] + c[2] + c[3];
}

__global__ void scan_blocks(const int* __restrict__ bcnt, int* __restrict__ baseA,
                            int* __restrict__ counts) {
  __shared__ int s[128];
  s[threadIdx.x] = bcnt[threadIdx.x];
  __syncthreads();
  if (threadIdx.x == 0) {
    int run = 0;
    for (int i = 0; i < 128; ++i) { int v = s[i]; s[i] = run; run += v; }
    counts[0] = run; counts[1] = NROWS - run;
  }
  __syncthreads();
  baseA[threadIdx.x] = s[threadIdx.x];
}

__global__ void write_idx(const int* __restrict__ masks, const int* __restrict__ baseA,
                          int* __restrict__ idxA, int* __restrict__ idxV) {
  int b = blockIdx.x, t = threadIdx.x, i = b * 256 + t;
  int lane = t & 63, wv = t >> 6;
  int r = masks[i * 3];
  unsigned long long vA = __ballot(r == 0);
  __shared__ int wc[4];
  if (lane == 0) wc[wv] = __popcll(vA);
  __syncthreads();
  int wA = 0;
#pragma unroll
  for (int w = 0; w < 4; ++w) if (w < wv) wA += wc[w];
  unsigned long long ltmask = (lane == 63) ? (~0ULL >> 1) : ((1ULL << lane) - 1);
  int posA = __popcll(vA & ltmask);
  int bA = baseA[b];
  if (r == 0) idxA[bA + wA + posA] = i;
  else        idxV[(256 * b - bA) + (64 * wv - wA) + (lane - posA)] = i;
}

// ---------- full-N compacted GEMM; LAYER in {1,2,3} ----------
// BM=128, BN=512 (FULL N -> A and h read exactly ONCE per layer), BK=64.
// 8 waves (2m x 4n), wave tile 64x128, acc 4x8 (128 VGPR). LDS 80 KB -> 2 blocks/CU.
// mlp pinned to XCD half (weights L2-resident); simple 2-barrier loop (round-4 base).
template <int LAYER>
__global__ __launch_bounds__(512, 1) void mlp_gemm(
    const float* __restrict__ audio, const float* __restrict__ visual,
    const float* __restrict__ text,  const float* __restrict__ kwd,
    const float* __restrict__ ctx,   const float* __restrict__ spk,
    const bf16*  __restrict__ hin,
    const bf16*  __restrict__ WTa,   const bf16* __restrict__ WTv,
    const float* __restrict__ ba,    const float* __restrict__ bv,
    const int*   __restrict__ counts,
    const int*   __restrict__ idxA,  const int* __restrict__ idxV,
    bf16* __restrict__ hout, float* __restrict__ out) {
  constexpr int K = (LAYER == 1) ? 1920 : 512;
  constexpr int NT = K / 64;
  const int bx = blockIdx.x;          // 0..271
  const int xcd = bx & 7;
  const int mlp = xcd >> 2;           // XCDs 0-3 -> mlp0, 4-7 -> mlp1 (L2 weight locality)
  const int mb = (xcd & 3) * 34 + (bx >> 3);  // 0..135 per mlp
  const int m0 = mb * 128;
  const int cnt = counts[mlp];
  if (m0 >= cnt) return;              // block-uniform early exit
  const bf16*  WT   = mlp ? WTv : WTa;
  const float* bias = mlp ? bv : ba;
  const int*   idx  = mlp ? idxV : idxA;

  __shared__ __attribute__((aligned(16))) bf16 sA[128 * 64];   // 16 KB
  __shared__ __attribute__((aligned(16))) bf16 sB[512 * 64];   // 64 KB

  const int t = threadIdx.x;
  const int lane = t & 63;
  const int wave = t >> 6;           // 0..7
  const int wm = (wave >> 2) * 64;   // 2 m-groups of 64 rows
  const int wn = (wave & 3) * 128;   // 4 n-groups of 128 cols
  const int cl = lane & 15;
  const int qw = lane >> 4;

  int gidx[2];
  if constexpr (LAYER == 1) {
#pragma unroll
    for (int rep = 0; rep < 2; ++rep) {
      int row = (t + rep * 512) >> 3;  // 0..127
      int i = m0 + row;
      if (i >= cnt) i = cnt - 1;  // clamp: duplicate row, discarded at store
      gidx[rep] = idx[i];
    }
  }

  auto B_ISSUE = [&](int k0) {  // 512 n-rows x 64 k: 8 gload per wave
#pragma unroll
    for (int j = 0; j < 8; ++j) {
      int sbase = (wave * 8 + j) * 64;       // wave-uniform
      int slot = sbase + lane;
      int row = slot >> 3, wc = slot & 7;    // row 0..511
      gload_lds16(WT + (size_t)row * K + k0 + wc * 8, &sB[sbase * 8]);
    }
  };
  auto A_ISSUE_LDS = [&](int k0) {  // 128 rows: 2 gload per wave
#pragma unroll
    for (int j = 0; j < 2; ++j) {
      int sbase = (wave * 2 + j) * 64;
      int slot = sbase + lane;
      int row = slot >> 3, wc = slot & 7;    // row 0..127
      gload_lds16(hin + ((size_t)mlp * PADM + m0 + row) * HID + k0 + wc * 8,
                  &sA[sbase * 8]);
    }
  };

  const f32x4 fzero = {0.f, 0.f, 0.f, 0.f};
  f32x4 acc[4][8];
#pragma unroll
  for (int a = 0; a < 4; ++a)
#pragma unroll
    for (int b = 0; b < 8; ++b) acc[a][b] = fzero;

  for (int ti = 0; ti < NT; ++ti) {
    const int k0 = ti * 64;
    __syncthreads();  // previous tile's fragment reads complete before overwrite
    B_ISSUE(k0);
    if constexpr (LAYER >= 2) {
      A_ISSUE_LDS(k0);
    } else {
      const float* seg; int soff, sstr;
      if (k0 < 512)       { seg = mlp ? audio : visual; soff = k0;        sstr = 512; }
      else if (k0 < 1280) { seg = text; soff = k0 - 512;  sstr = 768; }
      else if (k0 < 1536) { seg = kwd;  soff = k0 - 1280; sstr = 256; }
      else if (k0 < 1792) { seg = ctx;  soff = k0 - 1536; sstr = 256; }
      else                { seg = spk;  soff = k0 - 1792; sstr = 128; }
#pragma unroll
      for (int rep = 0; rep < 2; ++rep) {
        int slot = t + rep * 512;
        int row = slot >> 3, c = slot & 7;
        int wc = c ^ (row & 7);
        const float* src = seg + (size_t)gidx[rep] * sstr + soff + c * 8;
        f32x4 lo = *(const f32x4*)src;
        f32x4 hi = *(const f32x4*)(src + 4);
        bf16x8 v;
        v[0] = (bf16)lo[0]; v[1] = (bf16)lo[1]; v[2] = (bf16)lo[2]; v[3] = (bf16)lo[3];
        v[4] = (bf16)hi[0]; v[5] = (bf16)hi[1]; v[6] = (bf16)hi[2]; v[7] = (bf16)hi[3];
        *(bf16x8*)&sA[row * 64 + wc * 8] = v;
      }
    }
    __syncthreads();  // drains vmcnt (gload_lds) + lgkm (ds_write)

#pragma unroll
    for (int kh = 0; kh < 2; ++kh) {
      bf16x8 af[4];
#pragma unroll
      for (int mf = 0; mf < 4; ++mf) {
        int row = wm + mf * 16 + cl;
        int c = qw + kh * 4;
        af[mf] = *(const bf16x8*)&sA[row * 64 + ((c ^ (row & 7)) << 3)];
      }
#pragma unroll
      for (int nf = 0; nf < 8; ++nf) {
        int row = wn + nf * 16 + cl;
        int c = qw + kh * 4;
        bf16x8 bfr = *(const bf16x8*)&sB[row * 64 + ((c ^ (row & 7)) << 3)];
#pragma unroll
        for (int mf = 0; mf < 4; ++mf)
          acc[mf][nf] = __builtin_amdgcn_mfma_f32_16x16x32_bf16(
              af[mf], bfr, acc[mf][nf], 0, 0, 0);
      }
    }
  }

  // epilogue: C/D layout col = lane&15, row = (lane>>4)*4 + reg  [m89]
  const int r4 = qw * 4;
#pragma unroll
  for (int mf = 0; mf < 4; ++mf) {
#pragma unroll
    for (int reg = 0; reg < 4; ++reg) {
      int lrow = wm + mf * 16 + r4 + reg;
      int grow = m0 + lrow;
      if (grow >= cnt) continue;
      if constexpr (LAYER < 3) {
#pragma unroll
        for (int nf = 0; nf < 8; ++nf) {
          int col = wn + nf * 16 + cl;
          float v = acc[mf][nf][reg] + bias[col];
          v = fmaxf(v, 0.f);
          // store pre-swizzled so next layer's linear global_load_lds lands swizzled
          int cs = (col & ~63) | (((((col >> 3) & 7) ^ (grow & 7))) << 3) | (col & 7);
          hout[((size_t)mlp * PADM + grow) * HID + cs] = (bf16)v;
        }
      } else {
        int g = idx[grow];
#pragma unroll
        for (int nf = 0; nf < 8; ++nf) {
          int col = wn + nf * 16 + cl;
          float v = acc[mf][nf][reg] + bias[col];
          out[((size_t)mlp * NROWS + g) * 512 + col] = v;          // computed branch
          out[((size_t)(1 - mlp) * NROWS + g) * 512 + col] = 0.f;  // masked branch
        }
      }
    }
  }
}

extern "C" void kernel_launch(void* const* d_in, const int* in_sizes, int n_in,
                              void* d_out, int out_size, void* d_ws, size_t ws_size,
                              hipStream_t stream) {
  (void)in_sizes; (void)n_in; (void)out_size;
  const float* audio  = (const float*)d_in[0];
  const float* visual = (const float*)d_in[1];
  const float* text   = (const float*)d_in[2];
  const float* kwd    = (const float*)d_in[3];
  const float* ctx    = (const float*)d_in[4];
  const float* spk    = (const float*)d_in[5];
  const int*   masks  = (const int*)d_in[6];
  const float* aW1 = (const float*)d_in[7];  const float* ab1 = (const float*)d_in[8];
  const float* aW2 = (const float*)d_in[9];  const float* ab2 = (const float*)d_in[10];
  const float* aW3 = (const float*)d_in[11]; const float* ab3 = (const float*)d_in[12];
  const float* vW1 = (const float*)d_in[13]; const float* vb1 = (const float*)d_in[14];
  const float* vW2 = (const float*)d_in[15]; const float* vb2 = (const float*)d_in[16];
  const float* vW3 = (const float*)d_in[17]; const float* vb3 = (const float*)d_in[18];
  float* out = (float*)d_out;

  char* w = (char*)d_ws;
  int* counts = (int*)w;                       // 2 ints
  int* bcnt   = (int*)(w + 256);               // 128 ints
  int* baseA  = (int*)(w + 1024);              // 128 ints
  int* idxA = (int*)(w + 4096);
  int* idxV = idxA + 32768;
  bf16* aW1t = (bf16*)(w + 4096 + 262144);     // [512][1920] pre-swizzled
  bf16* vW1t = aW1t + 983040;
  bf16* aW2t = vW1t + 983040;                  // [512][512]
  bf16* vW2t = aW2t + 262144;
  bf16* aW3t = vW2t + 262144;
  bf16* vW3t = aW3t + 262144;
  bf16* h1 = vW3t + 262144;                    // [2][PADM][512] bf16, pre-swizzled
  bf16* h2 = h1 + (size_t)2 * PADM * HID;
  (void)ws_size;

  count_rows<<<128, 256, 0, stream>>>(masks, bcnt);
  scan_blocks<<<1, 128, 0, stream>>>(bcnt, baseA, counts);
  write_idx<<<128, 256, 0, stream>>>(masks, baseA, idxA, idxV);

  dim3 tb(32, 8);
  prep_transpose<<<dim3(60, 16), tb, 0, stream>>>(aW1, aW1t, 1920, 512);
  prep_transpose<<<dim3(60, 16), tb, 0, stream>>>(vW1, vW1t, 1920, 512);
  prep_transpose<<<dim3(16, 16), tb, 0, stream>>>(aW2, aW2t, 512, 512);
  prep_transpose<<<dim3(16, 16), tb, 0, stream>>>(vW2, vW2t, 512, 512);
  prep_transpose<<<dim3(16, 16), tb, 0, stream>>>(aW3, aW3t, 512, 512);
  prep_transpose<<<dim3(16, 16), tb, 0, stream>>>(vW3, vW3t, 512, 512);

  dim3 gg(272);  // 136 m-blocks x 2 mlps (mlp from XCD half); BN = full 512
  mlp_gemm<1><<<gg, 512, 0, stream>>>(audio, visual, text, kwd, ctx, spk, nullptr,
                                      aW1t, vW1t, ab1, vb1, counts, idxA, idxV, h1, nullptr);
  mlp_gemm<2><<<gg, 512, 0, stream>>>(audio, visual, text, kwd, ctx, spk, h1,
                                      aW2t, vW2t, ab2, vb2, counts, idxA, idxV, h2, nullptr);
  mlp_gemm<3><<<gg, 512, 0, stream>>>(audio, visual, text, kwd, ctx, spk, h2,
                                      aW3t, vW3t, ab3, vb3, counts, idxA, idxV, nullptr, out);
}

// Round 11
// 290.753 us; speedup vs baseline: 1.1869x; 1.1869x over previous
//
#include <hip/hip_runtime.h>
#include <stdint.h>

typedef __bf16 bf16;
typedef __bf16 bf16x8 __attribute__((ext_vector_type(8)));
typedef float  f32x4  __attribute__((ext_vector_type(4)));

#define NROWS 32768
#define HID   512
#define PADM  17408   // 68*256 rows per mlp (cnt = 16384 +/- 90; +11 sigma safe)

__device__ __forceinline__ void gload_lds16(const void* g, void* l) {
  __builtin_amdgcn_global_load_lds(
      (const __attribute__((address_space(1))) void*)g,
      (__attribute__((address_space(3))) void*)l, 16, 0, 0);
}

// ---------- prep: W [K][N] fp32 -> WT [N][K] bf16, 32k-group chunk-preswizzled ----------
// Within each 32-wide k-group (4 chunks of 8 bf16), logical chunk ch stored at slot
// ch ^ ((n>>1)&3): a LINEAR global_load_lds lands in the swizzled LDS layout the
// fragment reads expect (2-way bank aliasing = free).
__global__ void prep_transpose(const float* __restrict__ W, bf16* __restrict__ WT,
                               int K, int N) {
  __shared__ float t[32][33];
  int k0 = blockIdx.x * 32, n0 = blockIdx.y * 32;
  int tx = threadIdx.x, ty = threadIdx.y;
#pragma unroll
  for (int p = 0; p < 4; ++p)
    t[ty + p * 8][tx] = W[(size_t)(k0 + ty + p * 8) * N + n0 + tx];
  __syncthreads();
#pragma unroll
  for (int p = 0; p < 4; ++p) {
    int n = n0 + ty + p * 8;
    int k = k0 + tx;
    int ks = (k & ~31) | (((((k >> 3) & 3) ^ ((n >> 1) & 3))) << 3) | (k & 7);
    WT[(size_t)n * K + ks] = (bf16)t[tx][ty + p * 8];
  }
}

// ---------- sorted stable compaction: count -> scan -> ordered write ----------
__global__ void count_rows(const int* __restrict__ masks, int* __restrict__ bcnt) {
  int i = blockIdx.x * 256 + threadIdx.x;
  int lane = threadIdx.x & 63, wv = threadIdx.x >> 6;
  unsigned long long vA = __ballot(masks[i * 3] == 0);
  __shared__ int c[4];
  if (lane == 0) c[wv] = __popcll(vA);
  __syncthreads();
  if (threadIdx.x == 0) bcnt[blockIdx.x] = c[0] + c[1] + c[2] + c[3];
}

__global__ void scan_blocks(const int* __restrict__ bcnt, int* __restrict__ baseA,
                            int* __restrict__ counts) {
  __shared__ int s[128];
  s[threadIdx.x] = bcnt[threadIdx.x];
  __syncthreads();
  if (threadIdx.x == 0) {
    int run = 0;
    for (int i = 0; i < 128; ++i) { int v = s[i]; s[i] = run; run += v; }
    counts[0] = run; counts[1] = NROWS - run;
  }
  __syncthreads();
  baseA[threadIdx.x] = s[threadIdx.x];
}

__global__ void write_idx(const int* __restrict__ masks, const int* __restrict__ baseA,
                          int* __restrict__ idxA, int* __restrict__ idxV) {
  int b = blockIdx.x, t = threadIdx.x, i = b * 256 + t;
  int lane = t & 63, wv = t >> 6;
  int r = masks[i * 3];
  unsigned long long vA = __ballot(r == 0);
  __shared__ int wc[4];
  if (lane == 0) wc[wv] = __popcll(vA);
  __syncthreads();
  int wA = 0;
#pragma unroll
  for (int w = 0; w < 4; ++w) if (w < wv) wA += wc[w];
  unsigned long long ltmask = (lane == 63) ? (~0ULL >> 1) : ((1ULL << lane) - 1);
  int posA = __popcll(vA & ltmask);
  int bA = baseA[b];
  if (r == 0) idxA[bA + wA + posA] = i;
  else        idxV[(256 * b - bA) + (64 * wv - wA) + (lane - posA)] = i;
}

// ---------- ring-3 counted-vmcnt GEMM (T3/T4); LAYER in {1,2,3} ----------
// BM=256, BN=256, BK=32; 8 waves (2m x 4n), wave tile 128x64, acc 8x4.
// 3-tile LDS ring: W(t) computes buf[t%3]; stages tile t+2 into buf[(t+2)%3]
// (its occupant t-1 finished at end of W(t-1): provably dead -> race-free).
// End of W(t): s_waitcnt vmcnt(NLD) retires tile t+1's NLD loads (issued during
// W(t-1)), leaving this window's NLD in flight -> NEVER drains to 0 (T4). 1 barrier/tile.
// LAYER1: A staged as FP32 via gathered per-lane global_load_lds (sorted idx) and
// converted to bf16 at fragment-read time; NLD=6 (A 4 + B 2). LAYER>=2: NLD=4.
template <int LAYER>
__global__ __launch_bounds__(512, 2) void mlp_gemm(
    const float* __restrict__ audio, const float* __restrict__ visual,
    const float* __restrict__ text,  const float* __restrict__ kwd,
    const float* __restrict__ ctx,   const float* __restrict__ spk,
    const bf16*  __restrict__ hin,
    const bf16*  __restrict__ WTa,   const bf16* __restrict__ WTv,
    const float* __restrict__ ba,    const float* __restrict__ bv,
    const int*   __restrict__ counts,
    const int*   __restrict__ idxA,  const int* __restrict__ idxV,
    bf16* __restrict__ hout, float* __restrict__ out) {
  constexpr int K = (LAYER == 1) ? 1920 : 512;
  constexpr int NT = K / 32;
  const int mlp = blockIdx.z;
  const int cnt = counts[mlp];
  const int m0 = blockIdx.x * 256;
  if (m0 >= cnt) return;  // block-uniform early exit (before any barrier)
  const int n0 = blockIdx.y * 256;
  const bf16*  WT   = mlp ? WTv : WTa;
  const float* bias = mlp ? bv : ba;
  const int*   idx  = mlp ? idxV : idxA;

  // LDS: L1: A fp32 3x32KB + B bf16 3x16KB = 144KB; L>=2: 3x16 + 3x16 = 96KB
  constexpr int ABYTES = (LAYER == 1) ? 32768 : 16384;
  __shared__ __attribute__((aligned(16))) char smem[3 * ABYTES + 3 * 16384];
  char* sA = smem;
  bf16* sB = (bf16*)(smem + 3 * ABYTES);

  const int t = threadIdx.x;
  const int lane = t & 63;
  const int wave = t >> 6;           // 0..7
  const int wm = (wave >> 2) * 128;  // 2 m-groups of 128 rows
  const int wn = (wave & 3) * 64;    // 4 n-groups of 64 cols
  const int cl = lane & 15;
  const int qw = lane >> 4;          // 0..3

  // LAYER1 A-gather rows: per thread, its row for each of the 4 A G-loads (fixed over k)
  int gidxA[4];
  if constexpr (LAYER == 1) {
#pragma unroll
    for (int j = 0; j < 4; ++j) {
      int r = (((j * 8 + wave) * 64) + lane) >> 3;  // 0..255
      int i = m0 + r;
      if (i >= cnt) i = cnt - 1;  // clamp: duplicate valid row, discarded at store
      gidxA[j] = idx[i];
    }
  }

  auto STAGE = [&](int ti) {
    const int ring = ti % 3;
    const int k0 = ti * 32;
    // B: 16KB = 2 G-loads; dest linear, source pre-swizzled in WT storage
#pragma unroll
    for (int j = 0; j < 2; ++j) {
      int sbase = (j * 8 + wave) * 64;
      int slot = sbase + lane;
      int r = slot >> 2, c = slot & 3;           // r 0..255, 4 chunks/row
      gload_lds16(WT + (size_t)(n0 + r) * K + k0 + c * 8,
                  (char*)sB + ring * 16384 + slot * 16);
    }
    if constexpr (LAYER == 1) {
      // A fp32: 32KB = 4 G-loads; per-lane gathered + chunk-swizzled SOURCE (m173)
      const float* seg; int soff, sstr;
      if (k0 < 512)       { seg = mlp ? audio : visual; soff = k0;        sstr = 512; }
      else if (k0 < 1280) { seg = text; soff = k0 - 512;  sstr = 768; }
      else if (k0 < 1536) { seg = kwd;  soff = k0 - 1280; sstr = 256; }
      else if (k0 < 1792) { seg = ctx;  soff = k0 - 1536; sstr = 256; }
      else                { seg = spk;  soff = k0 - 1792; sstr = 128; }
#pragma unroll
      for (int j = 0; j < 4; ++j) {
        int sbase = (j * 8 + wave) * 64;
        int slot = sbase + lane;
        int r = slot >> 3, kc = slot & 7;        // r 0..255, 8 f32-chunks/row
        const float* src = seg + (size_t)gidxA[j] * sstr + soff + ((kc ^ (r & 7)) << 2);
        gload_lds16(src, sA + ring * 32768 + slot * 16);
      }
    } else {
      // A bf16 from h: 16KB = 2 G-loads; h stored pre-swizzled
#pragma unroll
      for (int j = 0; j < 2; ++j) {
        int sbase = (j * 8 + wave) * 64;
        int slot = sbase + lane;
        int r = slot >> 2, c = slot & 3;
        gload_lds16(hin + ((size_t)mlp * PADM + m0 + r) * HID + k0 + c * 8,
                    sA + ring * 16384 + slot * 16);
      }
    }
  };

  const f32x4 fzero = {0.f, 0.f, 0.f, 0.f};
  f32x4 acc[8][4];
#pragma unroll
  for (int a = 0; a < 8; ++a)
#pragma unroll
    for (int b = 0; b < 4; ++b) acc[a][b] = fzero;

  // ---- prologue: stage tiles 0,1; retire tile 0 (counted), keep tile 1 in flight ----
  STAGE(0);
  STAGE(1);
  if constexpr (LAYER == 1)
    asm volatile("s_waitcnt vmcnt(6)" ::: "memory");
  else
    asm volatile("s_waitcnt vmcnt(4)" ::: "memory");
  __builtin_amdgcn_s_barrier();

  for (int ti = 0; ti < NT; ++ti) {
    const int ring = ti % 3;
    STAGE((ti + 2 < NT) ? (ti + 2) : (NT - 1));  // clamped tail -> dead slots, uniform waits

    // B fragments: one per nf, shared across all mf (k = qw*8..+7)
    bf16x8 bfr[4];
#pragma unroll
    for (int nf = 0; nf < 4; ++nf) {
      int row = wn + nf * 16 + cl;
      bfr[nf] = *(const bf16x8*)(sB + ring * 8192 + row * 32 +
                                 ((qw ^ ((row >> 1) & 3)) << 3));
    }
    __builtin_amdgcn_s_setprio(1);
#pragma unroll
    for (int mf = 0; mf < 8; ++mf) {
      int row = wm + mf * 16 + cl;
      bf16x8 af;
      if constexpr (LAYER == 1) {
        const float* sAf = (const float*)sA + ring * 8192 + row * 32;
        f32x4 a0 = *(const f32x4*)(sAf + (((2 * qw) ^ (row & 7)) << 2));
        f32x4 a1 = *(const f32x4*)(sAf + (((2 * qw + 1) ^ (row & 7)) << 2));
        af[0] = (bf16)a0[0]; af[1] = (bf16)a0[1]; af[2] = (bf16)a0[2]; af[3] = (bf16)a0[3];
        af[4] = (bf16)a1[0]; af[5] = (bf16)a1[1]; af[6] = (bf16)a1[2]; af[7] = (bf16)a1[3];
      } else {
        af = *(const bf16x8*)((const bf16*)sA + ring * 8192 + row * 32 +
                              ((qw ^ ((row >> 1) & 3)) << 3));
      }
#pragma unroll
      for (int nf = 0; nf < 4; ++nf)
        acc[mf][nf] = __builtin_amdgcn_mfma_f32_16x16x32_bf16(
            af, bfr[nf], acc[mf][nf], 0, 0, 0);
    }
    __builtin_amdgcn_s_setprio(0);

    // retire tile ti+1's loads (issued last window); this window's stay in flight
    if constexpr (LAYER == 1)
      asm volatile("s_waitcnt vmcnt(6)" ::: "memory");
    else
      asm volatile("s_waitcnt vmcnt(4)" ::: "memory");
    __builtin_amdgcn_s_barrier();
  }
  asm volatile("s_waitcnt vmcnt(0)" ::: "memory");  // drain dangling tail stages

  // epilogue: C/D layout col = lane&15, row = (lane>>4)*4 + reg  [m89]
  const int r4 = qw * 4;
#pragma unroll
  for (int mf = 0; mf < 8; ++mf) {
#pragma unroll
    for (int reg = 0; reg < 4; ++reg) {
      int lrow = wm + mf * 16 + r4 + reg;
      int grow = m0 + lrow;
      if (grow >= cnt) continue;
      if constexpr (LAYER < 3) {
#pragma unroll
        for (int nf = 0; nf < 4; ++nf) {
          int col = n0 + wn + nf * 16 + cl;
          float v = acc[mf][nf][reg] + bias[col];
          v = fmaxf(v, 0.f);
          // store pre-swizzled (32k-group, ^((row>>1)&3)) for next layer's linear gload
          int cs = (col & ~31) | (((((col >> 3) & 3) ^ ((grow >> 1) & 3))) << 3) | (col & 7);
          hout[((size_t)mlp * PADM + grow) * HID + cs] = (bf16)v;
        }
      } else {
        int g = idx[grow];
#pragma unroll
        for (int nf = 0; nf < 4; ++nf) {
          int col = n0 + wn + nf * 16 + cl;
          float v = acc[mf][nf][reg] + bias[col];
          out[((size_t)mlp * NROWS + g) * 512 + col] = v;          // computed branch
          out[((size_t)(1 - mlp) * NROWS + g) * 512 + col] = 0.f;  // masked branch
        }
      }
    }
  }
}

extern "C" void kernel_launch(void* const* d_in, const int* in_sizes, int n_in,
                              void* d_out, int out_size, void* d_ws, size_t ws_size,
                              hipStream_t stream) {
  (void)in_sizes; (void)n_in; (void)out_size;
  const float* audio  = (const float*)d_in[0];
  const float* visual = (const float*)d_in[1];
  const float* text   = (const float*)d_in[2];
  const float* kwd    = (const float*)d_in[3];
  const float* ctx    = (const float*)d_in[4];
  const float* spk    = (const float*)d_in[5];
  const int*   masks  = (const int*)d_in[6];
  const float* aW1 = (const float*)d_in[7];  const float* ab1 = (const float*)d_in[8];
  const float* aW2 = (const float*)d_in[9];  const float* ab2 = (const float*)d_in[10];
  const float* aW3 = (const float*)d_in[11]; const float* ab3 = (const float*)d_in[12];
  const float* vW1 = (const float*)d_in[13]; const float* vb1 = (const float*)d_in[14];
  const float* vW2 = (const float*)d_in[15]; const float* vb2 = (const float*)d_in[16];
  const float* vW3 = (const float*)d_in[17]; const float* vb3 = (const float*)d_in[18];
  float* out = (float*)d_out;

  char* w = (char*)d_ws;
  int* counts = (int*)w;                       // 2 ints
  int* bcnt   = (int*)(w + 256);               // 128 ints
  int* baseA  = (int*)(w + 1024);              // 128 ints
  int* idxA = (int*)(w + 4096);
  int* idxV = idxA + 32768;
  bf16* aW1t = (bf16*)(w + 4096 + 262144);     // [512][1920] pre-swizzled (32k-groups)
  bf16* vW1t = aW1t + 983040;
  bf16* aW2t = vW1t + 983040;                  // [512][512]
  bf16* vW2t = aW2t + 262144;
  bf16* aW3t = vW2t + 262144;
  bf16* vW3t = aW3t + 262144;
  bf16* h1 = vW3t + 262144;                    // [2][PADM][512] bf16, pre-swizzled
  bf16* h2 = h1 + (size_t)2 * PADM * HID;
  (void)ws_size;

  count_rows<<<128, 256, 0, stream>>>(masks, bcnt);
  scan_blocks<<<1, 128, 0, stream>>>(bcnt, baseA, counts);
  write_idx<<<128, 256, 0, stream>>>(masks, baseA, idxA, idxV);

  dim3 tb(32, 8);
  prep_transpose<<<dim3(60, 16), tb, 0, stream>>>(aW1, aW1t, 1920, 512);
  prep_transpose<<<dim3(60, 16), tb, 0, stream>>>(vW1, vW1t, 1920, 512);
  prep_transpose<<<dim3(16, 16), tb, 0, stream>>>(aW2, aW2t, 512, 512);
  prep_transpose<<<dim3(16, 16), tb, 0, stream>>>(vW2, vW2t, 512, 512);
  prep_transpose<<<dim3(16, 16), tb, 0, stream>>>(aW3, aW3t, 512, 512);
  prep_transpose<<<dim3(16, 16), tb, 0, stream>>>(vW3, vW3t, 512, 512);

  dim3 gg(68, 2, 2);  // 68 m-blocks of 256 x 2 n-blocks of 256 x 2 mlps (~256 active)
  mlp_gemm<1><<<gg, 512, 0, stream>>>(audio, visual, text, kwd, ctx, spk, nullptr,
                                      aW1t, vW1t, ab1, vb1, counts, idxA, idxV, h1, nullptr);
  mlp_gemm<2><<<gg, 512, 0, stream>>>(audio, visual, text, kwd, ctx, spk, h1,
                                      aW2t, vW2t, ab2, vb2, counts, idxA, idxV, h2, nullptr);
  mlp_gemm<3><<<gg, 512, 0, stream>>>(audio, visual, text, kwd, ctx, spk, h2,
                                      aW3t, vW3t, ab3, vb3, counts, idxA, idxV, nullptr, out);
}